// Round 11
// baseline (1849.094 us; speedup 1.0000x reference)
//
#include <hip/hip_runtime.h>
#include <cmath>

// DHT: out[n,c,a,r] = sum over px (x,y) of feat[n,c,y,x],
//   r = rint((x-128)*cos(a deg) + (y-128)*sin(a deg)) + 361  (r in [180,542])
// feat[4,128,256,256] f32 -> out[4,128,180,723] f32.
//
// Locked-in findings:
//  R1-R4 (~31ms): LDS f32 atomicAdd serializes ~per-lane -> never on hot path.
//  R5 (2.69ms): wave-private rows + 4-col lane stride + plain program-ordered
//    DS RMW (race-free: lane bin spacing 4|coef|>=2.83 -> distinct bins).
//  R6 (3.88ms): >1 block/CU with chunked re-reads -> HBM-bound.
//  R7 (1.85ms): register-persistent px across ALL angles (FETCH 0.6GB).
//  R8 (1.66ms): quarter swizzle e=(b>>2)+(b&3)*QW. Budget closes: port
//    2.95M cyc + walk conflicts 1.0M + flush conflicts 0.1M.
//  R9 (1.84ms, REVERTED): QW=100 b64 rotation hurt walk; e-space flush
//    scattered global atomics.
//  R10 (1.78ms, REVERTED): exec-masked run-merge cut conflicts but broke the
//    dense RMW issue stream -> branches around DS RMW are poison.
//  R11: b32 RMWs (1 image/block, f32 rows): port bytes invariant but b32
//    conflict floor is benign (m136: 2-way free); within-quarter word-stride
//    = |coef| in [0.707,1] -> ~dense. QW=104: quarter offsets {0,8,16,24}
//    mod 32 -> the 4 quarter-clouds tile all banks (also fixes flush reads).
//    2 blocks/CU (53KB rows) -> 32 waves; __launch_bounds__(1024,8) caps
//    VGPR at 64 (px now 32 regs).

#define NA 180
#define NR 723
#define HW 65536
#define NC 512
#define CH 2            // angles per LDS chunk
#define ROW_W 368       // bins rl = r-RBASE in [4,366]
#define QW 104          // quarter width (f32): offsets {0,104,208,312} == {0,8,16,24} mod 32
#define ROW_PAD 416     // 4 quarters x 104 (rows: 16*2*416*4B = 53.2 KB)
#define RBASE 176
#define NWIN 32         // 8-px windows along the scan axis

__device__ __forceinline__ bool is_phase2(int a) { return a >= 46 && a <= 134; }

// bijective swizzle inside a 416-element row; max e = 91 + 3*104 = 403 < 416
__device__ __forceinline__ int swz(int b) { return (b >> 2) + (b & 3) * QW; }

// ---------------------------------------------------------------------------
// win[a][w][fast] u32 = base bin at scan=8w (bits 0..15), step bits 16..22.
// Phase-1 (a in [0,45]u[135,179]): fast=x, scan=y (step coef sin(a)>=0).
// Phase-2 (a in [46,134]):         fast=y, scan=x (step coef cos(a), sign
// flips at a=90). fp64 non-fused mul/add + rint bit-matches np.round
// (validated R1-R10: absmax 0.25 = f32 sum-order noise only).
// ---------------------------------------------------------------------------
__global__ __launch_bounds__(256) void dht_win(unsigned int* __restrict__ win) {
    const int lane = threadIdx.x;
    const int w = blockIdx.x;
    const int a = blockIdx.y;
    const double theta = (double)a * (M_PI / 180.0);
    const double c = cos(theta), s = sin(theta);
    const bool p2 = is_phase2(a);
    int prev = 0;
    unsigned int word = 0;
    #pragma unroll
    for (int i = 0; i < 8; ++i) {
        const int k = w * 8 + i;
        const int x = p2 ? k : lane;
        const int y = p2 ? lane : k;
        const double rho = __dadd_rn(__dmul_rn((double)(x - 128), c),
                                     __dmul_rn((double)(y - 128), s));
        int r = (int)rint(rho) + 361;
        r = min(max(r, 0), NR - 1);
        if (i == 0) word = (unsigned int)r;
        else if (r != prev) word |= (1u << (15 + i));
        prev = r;
    }
    win[((size_t)a * NWIN + w) * 256 + lane] = word;
}

__global__ __launch_bounds__(256) void zero_out(float4* __restrict__ o, int n4) {
    const int i = blockIdx.x * 256 + threadIdx.x;
    if (i < n4) o[i] = make_float4(0.f, 0.f, 0.f, 0.f);
}

// Branchless 8(scan) x 4(col) walk, b32 RMWs. Concurrent lanes 4 columns
// apart -> bins >= 2.83 apart -> distinct (bijective swizzle preserves it).
// Dense unconditional RMW stream (R10: branches around DS are poison).
template <int SGN>
__device__ __forceinline__ void walk1(const uint4 wq, const float (&px)[8][4],
                                      float* __restrict__ rp) {
    #pragma unroll
    for (int j = 0; j < 4; ++j) {
        const unsigned int wrd = (&wq.x)[j];
        int bin = (int)(wrd & 0xffffu) - RBASE;
        #pragma unroll
        for (int k = 0; k < 8; ++k) {
            if (k) bin += SGN * (int)((wrd >> (15 + k)) & 1u);
            rp[swz(bin)] += px[k][j];
        }
    }
}

// ---------------------------------------------------------------------------
// Block = (image, phase, scan-half). 1024 thr = 16 waves; wave wv owns scan
// window w = 16h+wv (8 scan lines); lane owns 4 fast columns 4l..4l+3.
// px f32[8][4] (32 regs) loaded ONCE, reused across all angles of the phase.
// rows[16 waves][CH][ROW_PAD] f32 = 53.2 KB -> 2 blocks/CU = 32 waves.
// ---------------------------------------------------------------------------
__global__ __launch_bounds__(1024, 8) void dht_main(const float* __restrict__ feat,
                                                    const unsigned int* __restrict__ win,
                                                    float* __restrict__ out) {
    __shared__ float rows[16 * CH * ROW_PAD];   // 53.2 KB
    const int t = threadIdx.x;
    const int wv = t >> 6;
    const int l = t & 63;
    const int img = blockIdx.x;
    const int phase = blockIdx.y;
    const int h = blockIdx.z;
    const int w = 16 * h + wv;          // scan window 0..31
    const int k0 = 8 * w;               // scan offset
    const float* __restrict__ f0 = feat + (size_t)img * HW;
    float* __restrict__ o0 = out + (size_t)img * (NA * NR);

    // ---- load persistent px tile: 8 scan x 4 col ----
    float px[8][4];
    if (phase == 0) {
        // scan=y: rows y=k0+k, cols x=4l..4l+3 (fully coalesced float4)
        #pragma unroll
        for (int k = 0; k < 8; ++k) {
            const float4 q = *(const float4*)(f0 + ((k0 + k) << 8) + 4 * l);
            px[k][0] = q.x; px[k][1] = q.y; px[k][2] = q.z; px[k][3] = q.w;
        }
    } else {
        // scan=x: rows y=4l+j, cols x=k0..k0+7 (2 aligned float4 per row)
        #pragma unroll
        for (int j = 0; j < 4; ++j) {
            const float4 q0 = *(const float4*)(f0 + ((4 * l + j) << 8) + k0);
            const float4 q1 = *(const float4*)(f0 + ((4 * l + j) << 8) + k0 + 4);
            px[0][j] = q0.x; px[1][j] = q0.y; px[2][j] = q0.z; px[3][j] = q0.w;
            px[4][j] = q1.x; px[5][j] = q1.y; px[6][j] = q1.z; px[7][j] = q1.w;
        }
    }

    const int nAng = phase ? 89 : 91;
    for (int cb = 0; cb < nAng; cb += CH) {
        const int cn = min(CH, nAng - cb);
        for (int i = t; i < 16 * CH * ROW_PAD; i += 1024) rows[i] = 0.f;
        __syncthreads();

        for (int ai = 0; ai < cn; ++ai) {
            const int aidx = cb + ai;
            const int a = phase ? (46 + aidx) : (aidx <= 45 ? aidx : aidx + 89);
            const uint4 wq = *(const uint4*)(win + ((size_t)a * NWIN + w) * 256 + 4 * l);
            float* __restrict__ rp = rows + (wv * CH + ai) * ROW_PAD;
            if (phase && a > 90) walk1<-1>(wq, px, rp);
            else                 walk1<+1>(wq, px, rp);
        }
        __syncthreads();

        // flush: lanes iterate rl contiguously -> contiguous global atomics;
        // LDS read at swz(rl): lanes 0-3 hit ad {0,104,208,312} == banks
        // {0,8,16,24} -> spread (QW=104 fixes the old 4-way flush read).
        // Exactly-2 atomic contributions per out element -> deterministic.
        for (int i = t; i < cn * ROW_W; i += 1024) {
            const int al = i / ROW_W;
            const int rl = i - al * ROW_W;
            const int ad = swz(rl);
            float s = 0.f;
            #pragma unroll
            for (int c2 = 0; c2 < 16; ++c2)
                s += rows[(c2 * CH + al) * ROW_PAD + ad];
            const int aidx = cb + al;
            const int a = phase ? (46 + aidx) : (aidx <= 45 ? aidx : aidx + 89);
            unsafeAtomicAdd(o0 + (size_t)a * NR + (RBASE + rl), s);
        }
        __syncthreads();
    }
}

extern "C" void kernel_launch(void* const* d_in, const int* in_sizes, int n_in,
                              void* d_out, int out_size, void* d_ws, size_t ws_size,
                              hipStream_t stream) {
    const float* feat = (const float*)d_in[0];
    float* out = (float*)d_out;
    unsigned int* win = (unsigned int*)d_ws;

    const size_t win_bytes = (size_t)NA * NWIN * 256 * sizeof(unsigned int); // 5.9MB
    if (ws_size < win_bytes) return;

    const int n4 = out_size / 4;   // out_size = 512*180*723, divisible by 4
    hipLaunchKernelGGL(zero_out, dim3((n4 + 255) / 256), dim3(256), 0, stream,
                       (float4*)out, n4);
    hipLaunchKernelGGL(dht_win, dim3(NWIN, NA), dim3(256), 0, stream, win);
    hipLaunchKernelGGL(dht_main, dim3(NC, 2, 2), dim3(1024), 0, stream,
                       feat, win, out);
}

// Round 12
// 1500.077 us; speedup vs baseline: 1.2327x; 1.2327x over previous
//
#include <hip/hip_runtime.h>
#include <cmath>

// DHT: out[n,c,a,r] = sum over px (x,y) of feat[n,c,y,x],
//   r = rint((x-128)*cos(a deg) + (y-128)*sin(a deg)) + 361  (r in [180,542])
// feat[4,128,256,256] f32 -> out[4,128,180,723] f32.
//
// Locked-in findings:
//  R1-R4 (~31ms): LDS f32 atomicAdd serializes ~per-lane -> never on hot path.
//  R5 (2.69ms): wave-private rows + plain program-ordered DS RMW, race-free
//    when concurrent lanes' bins provably distinct.
//  R6 (3.88ms): image re-reads at >1 block/CU -> HBM-bound. R9/R11: swizzle
//    numerology failed 3x; occupancy is NOT the binding resource (R11: 92%
//    occ, slower). R10: exec-masked/branchy DS RMW poison.
//  R7 (1.85ms): register-persistent px across ALL angles (FETCH 0.6GB).
//  R8 (1.66ms): b64 image-pair RMW + quarter swizzle. Budget: port floor
//    1.47M cyc + conflicts 1.12M + VALU ~0.9M + flush ~0.4M.
//  R12: conflict fix by GEOMETRY: lane column-stride 2 (was 4). Bin spacing
//    2|coef| in [1.41,2] -> still distinct (race-free), b64 word-stride
//    drops to 2.83-4 (dense regime, ~1.58x by m136). Swizzle dropped
//    (3 VALU/visit saved; flush reads stride-2 = free).

#define NA 180
#define NR 723
#define HW 65536
#define NC 512
#define CH 2            // angles per LDS chunk
#define ROW_W 368       // bins rl = r-RBASE in [4,366]
#define ROW_PAD 368     // no swizzle, no pad needed
#define RBASE 176
#define NWIN 32         // 8-px windows along the scan axis

__device__ __forceinline__ bool is_phase2(int a) { return a >= 46 && a <= 134; }

// ---------------------------------------------------------------------------
// win[a][w][fast] u32 = base bin at scan=8w (bits 0..15), step bits 16..22.
// Phase-1 (a in [0,45]u[135,179]): fast=x, scan=y (step coef sin(a)>=0).
// Phase-2 (a in [46,134]):         fast=y, scan=x (step coef cos(a), sign
// flips at a=90). fp64 non-fused mul/add + rint bit-matches np.round
// (validated R1-R11: absmax 0.25 = f32 sum-order noise only).
// ---------------------------------------------------------------------------
__global__ __launch_bounds__(256) void dht_win(unsigned int* __restrict__ win) {
    const int lane = threadIdx.x;
    const int w = blockIdx.x;
    const int a = blockIdx.y;
    const double theta = (double)a * (M_PI / 180.0);
    const double c = cos(theta), s = sin(theta);
    const bool p2 = is_phase2(a);
    int prev = 0;
    unsigned int word = 0;
    #pragma unroll
    for (int i = 0; i < 8; ++i) {
        const int k = w * 8 + i;
        const int x = p2 ? k : lane;
        const int y = p2 ? lane : k;
        const double rho = __dadd_rn(__dmul_rn((double)(x - 128), c),
                                     __dmul_rn((double)(y - 128), s));
        int r = (int)rint(rho) + 361;
        r = min(max(r, 0), NR - 1);
        if (i == 0) word = (unsigned int)r;
        else if (r != prev) word |= (1u << (15 + i));
        prev = r;
    }
    win[((size_t)a * NWIN + w) * 256 + lane] = word;
}

__global__ __launch_bounds__(256) void zero_out(float4* __restrict__ o, int n4) {
    const int i = blockIdx.x * 256 + threadIdx.x;
    if (i < n4) o[i] = make_float4(0.f, 0.f, 0.f, 0.f);
}

// Branchless 8(scan) x 4(col) x 2(img) walk, b64 RMW, unswizzled.
// Concurrent lanes (fixed j) sit 2 columns apart -> bin spacing
// 2|coef| >= 1.414 -> distinct addresses -> race-free (program-ordered
// same-wave DS). Dense unconditional RMW stream.
template <int SGN>
__device__ __forceinline__ void walk2(const uint4 wq, const float2 (&px)[8][4],
                                      float2* __restrict__ rp) {
    #pragma unroll
    for (int j = 0; j < 4; ++j) {
        const unsigned int wrd = (&wq.x)[j];
        int bin = (int)(wrd & 0xffffu) - RBASE;
        #pragma unroll
        for (int k = 0; k < 8; ++k) {
            if (k) bin += SGN * (int)((wrd >> (15 + k)) & 1u);
            float2 v = rp[bin];
            v.x += px[k][j].x;
            v.y += px[k][j].y;
            rp[bin] = v;
        }
    }
}

// ---------------------------------------------------------------------------
// Block = (image-pair, phase, scan-half). 1024 thr = 16 waves; wave wv owns
// scan window w = 16h+wv (8 scan lines); lane owns fast columns
// {2l, 2l+1, 2l+128, 2l+129} (j = 0..3 in that order). px float2[8][4]
// loaded ONCE, reused across all angles of the phase.
// rows[16 waves][CH][ROW_PAD] float2 = 94.2 KB -> 1 block/CU.
// ---------------------------------------------------------------------------
__global__ __launch_bounds__(1024, 4) void dht_main(const float* __restrict__ feat,
                                                    const unsigned int* __restrict__ win,
                                                    float* __restrict__ out) {
    __shared__ float2 rows[16 * CH * ROW_PAD];   // 94.2 KB
    const int t = threadIdx.x;
    const int wv = t >> 6;
    const int l = t & 63;
    const int pair = blockIdx.x;
    const int phase = blockIdx.y;
    const int h = blockIdx.z;
    const int w = 16 * h + wv;          // scan window 0..31
    const int k0 = 8 * w;               // scan offset
    const float* __restrict__ f0 = feat + (size_t)(2 * pair) * HW;
    const float* __restrict__ f1 = feat + (size_t)(2 * pair + 1) * HW;
    float* __restrict__ o0 = out + (size_t)(2 * pair) * (NA * NR);
    float* __restrict__ o1 = out + (size_t)(2 * pair + 1) * (NA * NR);

    // fast-axis indices owned by this lane (j = 0..3)
    const int fj0 = 2 * l;        // and fj0+1
    const int fj2 = 2 * l + 128;  // and fj2+1

    // ---- load persistent px tile: 8 scan x 4 fast x 2 img ----
    float2 px[8][4];
    if (phase == 0) {
        // scan=y: row y=k0+k; fast=x at {2l,2l+1} and {2l+128,2l+129}
        // (two float2 loads per row per image; lanes dense -> coalesced)
        #pragma unroll
        for (int k = 0; k < 8; ++k) {
            const float2 a0 = *(const float2*)(f0 + ((k0 + k) << 8) + fj0);
            const float2 a1 = *(const float2*)(f0 + ((k0 + k) << 8) + fj2);
            const float2 b0 = *(const float2*)(f1 + ((k0 + k) << 8) + fj0);
            const float2 b1 = *(const float2*)(f1 + ((k0 + k) << 8) + fj2);
            px[k][0] = make_float2(a0.x, b0.x); px[k][1] = make_float2(a0.y, b0.y);
            px[k][2] = make_float2(a1.x, b1.x); px[k][3] = make_float2(a1.y, b1.y);
        }
    } else {
        // scan=x: fast=y rows {2l,2l+1,2l+128,2l+129}; cols x=k0..k0+7
        #pragma unroll
        for (int j = 0; j < 4; ++j) {
            const int fr = (j < 2) ? (fj0 + j) : (fj2 + (j - 2));
            const float4 q0 = *(const float4*)(f0 + (fr << 8) + k0);
            const float4 q1 = *(const float4*)(f0 + (fr << 8) + k0 + 4);
            const float4 r0 = *(const float4*)(f1 + (fr << 8) + k0);
            const float4 r1 = *(const float4*)(f1 + (fr << 8) + k0 + 4);
            px[0][j] = make_float2(q0.x, r0.x); px[1][j] = make_float2(q0.y, r0.y);
            px[2][j] = make_float2(q0.z, r0.z); px[3][j] = make_float2(q0.w, r0.w);
            px[4][j] = make_float2(q1.x, r1.x); px[5][j] = make_float2(q1.y, r1.y);
            px[6][j] = make_float2(q1.z, r1.z); px[7][j] = make_float2(q1.w, r1.w);
        }
    }

    const int nAng = phase ? 89 : 91;
    for (int cb = 0; cb < nAng; cb += CH) {
        const int cn = min(CH, nAng - cb);
        for (int i = t; i < 16 * CH * ROW_PAD; i += 1024)
            rows[i] = make_float2(0.f, 0.f);
        __syncthreads();

        for (int ai = 0; ai < cn; ++ai) {
            const int aidx = cb + ai;
            const int a = phase ? (46 + aidx) : (aidx <= 45 ? aidx : aidx + 89);
            const unsigned int* wrow = win + ((size_t)a * NWIN + w) * 256;
            const uint2 u0 = *(const uint2*)(wrow + fj0);   // cols 2l, 2l+1
            const uint2 u1 = *(const uint2*)(wrow + fj2);   // cols 2l+128, 2l+129
            uint4 wq; wq.x = u0.x; wq.y = u0.y; wq.z = u1.x; wq.w = u1.y;
            float2* __restrict__ rp = rows + (wv * CH + ai) * ROW_PAD;
            if (phase && a > 90) walk2<-1>(wq, px, rp);
            else                 walk2<+1>(wq, px, rp);
        }
        __syncthreads();

        // flush: lanes iterate rl contiguously -> stride-2-word LDS reads
        // (free) and contiguous global atomics. Exactly-2 atomic
        // contributions per out element (two scan-halves) -> deterministic.
        for (int i = t; i < cn * ROW_W; i += 1024) {
            const int al = i / ROW_W;
            const int rl = i - al * ROW_W;
            float sx = 0.f, sy = 0.f;
            #pragma unroll
            for (int c2 = 0; c2 < 16; ++c2) {
                const float2 v = rows[(c2 * CH + al) * ROW_PAD + rl];
                sx += v.x; sy += v.y;
            }
            const int aidx = cb + al;
            const int a = phase ? (46 + aidx) : (aidx <= 45 ? aidx : aidx + 89);
            const size_t o = (size_t)a * NR + (RBASE + rl);
            unsafeAtomicAdd(o0 + o, sx);
            unsafeAtomicAdd(o1 + o, sy);
        }
        __syncthreads();
    }
}

extern "C" void kernel_launch(void* const* d_in, const int* in_sizes, int n_in,
                              void* d_out, int out_size, void* d_ws, size_t ws_size,
                              hipStream_t stream) {
    const float* feat = (const float*)d_in[0];
    float* out = (float*)d_out;
    unsigned int* win = (unsigned int*)d_ws;

    const size_t win_bytes = (size_t)NA * NWIN * 256 * sizeof(unsigned int); // 5.9MB
    if (ws_size < win_bytes) return;

    const int n4 = out_size / 4;   // out_size = 512*180*723, divisible by 4
    hipLaunchKernelGGL(zero_out, dim3((n4 + 255) / 256), dim3(256), 0, stream,
                       (float4*)out, n4);
    hipLaunchKernelGGL(dht_win, dim3(NWIN, NA), dim3(256), 0, stream, win);
    hipLaunchKernelGGL(dht_main, dim3(NC / 2, 2, 2), dim3(1024), 0, stream,
                       feat, win, out);
}